// Round 3
// baseline (128.311 us; speedup 1.0000x reference)
//
#include <hip/hip_runtime.h>
#include <hip/hip_bf16.h>

typedef __attribute__((ext_vector_type(4))) float f32x4;
typedef __attribute__((ext_vector_type(8))) __bf16 bf16x8;
typedef __attribute__((ext_vector_type(4))) unsigned int uint4v;

constexpr int M = 16384;
constexpr int N = 1024;
constexpr int K = 2048;
constexpr int BM = 256, BN = 256, BK = 64;  // 8-phase 256^2 template, BK=64
constexpr int NK2 = K / BK;                 // 32 K-tiles
constexpr float BN_EPS = 1e-5f;
constexpr int TM2 = M / BM;                // 64 row-tiles (psum partials)
constexpr int GRID = (M / BM) * (N / BN);  // 256 blocks = 1/CU

// async 16B global -> LDS (lds dest must be wave-uniform; HW adds lane*16)
#define GLOAD_LDS16(g, l)                                                      \
  __builtin_amdgcn_global_load_lds(                                            \
      (const __attribute__((address_space(1))) void*)(g),                      \
      (__attribute__((address_space(3))) void*)(l), 16, 0, 0)

#define SB0 __builtin_amdgcn_sched_barrier(0)
#define BARRIER __builtin_amdgcn_s_barrier()
#define VMC(n) asm volatile("s_waitcnt vmcnt(" #n ")" ::: "memory")
#define LGKM0 asm volatile("s_waitcnt lgkmcnt(0)" ::: "memory")

__device__ __forceinline__ unsigned sgnbf(float f) {
  return (f >= 0.f) ? 0x3F80u : 0xBF80u;
}
__global__ __launch_bounds__(256) void binw_kernel(
    const float* __restrict__ w, uint4v* __restrict__ wb,
    unsigned* __restrict__ ctr) {
  if (blockIdx.x == 0 && threadIdx.x < 8) ctr[threadIdx.x] = 0;  // ctr+flag
  size_t i = (size_t)blockIdx.x * 256 + threadIdx.x;
  const f32x4* win = (const f32x4*)w;
  f32x4 v0 = win[i * 2];
  f32x4 v1 = win[i * 2 + 1];
  uint4v o;
  o.x = sgnbf(v0[0]) | (sgnbf(v0[1]) << 16);
  o.y = sgnbf(v0[2]) | (sgnbf(v0[3]) << 16);
  o.z = sgnbf(v1[0]) | (sgnbf(v1[1]) << 16);
  o.w = sgnbf(v1[2]) | (sgnbf(v1[3]) << 16);
  wb[i] = o;
}

// ---- bf16 GEMM, m201-style 8-phase schedule, fused BatchNorm tail ----
// 512 thr = 8 waves (2M x 4N), wave tile 128x64, BK=64, 2-slot LDS dbuf.
// Per K-tile: 4 phases x {ds-read subtile; stage; barrier; lgkm0; setprio;
// 16 MFMA; setprio; barrier}. Counted vmcnt: every wait targets loads
// issued >=2 phases earlier. A = x fp32 (reg-stage + cvt + swizzled
// ds_write); B = w_bin bf16 (gload_lds, pre-swizzled global source).
// LDS rows are 64 bf16 = 128 B: chunk ^= (row&7) spreads the 8 16B-chunks
// -> 8 lanes/bank-quad per b128 read = bank-even (conflict-free).
// Tail: per-tn-group (64 blocks) ticket; last arriver reduces psum ->
// scale/shift (2 KB), others spin on flag; apply to live acc, store Y once.
__global__ __launch_bounds__(512) void gemm_bin_kernel(
    const float* __restrict__ Af, const unsigned short* __restrict__ B,
    float* __restrict__ Y, float* __restrict__ psum, float* __restrict__ psq,
    float* __restrict__ scale, float* __restrict__ shift,
    const float* __restrict__ gamma, const float* __restrict__ beta,
    unsigned* __restrict__ ctr) {
  __shared__ unsigned short As[2][BM * BK];  // 64 KiB
  __shared__ unsigned short Bs[2][BN * BK];  // 64 KiB
  __shared__ float redsum[2][BN];            // 2 KiB (reused 3x)
  __shared__ float redsq[2][BN];             // 2 KiB
  __shared__ unsigned sh_tkt;

  const int tid = threadIdx.x;
  const int wid = tid >> 6;
  const int lane = tid & 63;
  const int wr = wid >> 2, wc = wid & 3;  // 2x4 wave grid, wave owns 128x64

  // T1: XCD swizzle (grid 256, %8==0): XCD owns contiguous tm range.
  const int bid = blockIdx.x;
  const int swz = (bid & 7) * 32 + (bid >> 3);
  const int tm = swz >> 2, tn = swz & 3;
  const size_t m0 = (size_t)tm * BM, n0 = (size_t)tn * BN;

  const int frow = lane & 15;  // fragment row/col within 16x16
  const int fcb = lane >> 4;   // k chunk 0..3
  const int f7 = frow & 7;
  // read offsets (ushort idx): row*64 + swizzled-chunk*8; ks selects k 0..31/32..63
  const int aoff0 = (wr * 128 + frow) * 64 + (fcb ^ f7) * 8;
  const int aoff1 = (wr * 128 + frow) * 64 + ((4 + fcb) ^ f7) * 8;
  const int boff0 = (wc * 64 + frow) * 64 + (fcb ^ f7) * 8;
  const int boff1 = (wc * 64 + frow) * 64 + ((4 + fcb) ^ f7) * 8;

  f32x4 acc[8][4];
#pragma unroll
  for (int mi = 0; mi < 8; ++mi)
#pragma unroll
    for (int nj = 0; nj < 4; ++nj)
#pragma unroll
      for (int j = 0; j < 4; ++j) acc[mi][nj][j] = 0.f;

  // B staging (gload_lds, pre-swizzled source): round rd covers rows
  // rd*64 + wid*8 .. +7; lane: row += lane>>3, global chunk = (lane&7)^(row&7).
  const int rbase = wid * 8 + (lane >> 3);
  const int cg = (lane & 7) ^ ((lane >> 3) & 7);
  const unsigned short* pBg = B + (n0 + rbase) * (size_t)K + cg * 8;

  // A staging (reg+cvt): thread t: row rA = t>>1, half hA = t&1; per chunk
  // group g loads global chunk 2g+hA (8 floats), writes LDS chunk (2g+hA)^(rA&7).
  const int rA = tid >> 1;
  const int hA = tid & 1;
  const int hA8 = hA * 8;
  const float* pA = Af + (m0 + rA) * (size_t)K;
  const int awb0 = rA * 64 + ((0 + hA) ^ (rA & 7)) * 8;
  const int awb1 = rA * 64 + ((2 + hA) ^ (rA & 7)) * 8;
  const int awb2 = rA * 64 + ((4 + hA) ^ (rA & 7)) * 8;
  const int awb3 = rA * 64 + ((6 + hA) ^ (rA & 7)) * 8;

#define AL(g, ktv, R0, R1)                                                     \
  {                                                                            \
    const float* p_ = pA + (size_t)(ktv)*64 + (g)*16 + hA8;                    \
    R0 = *(const f32x4*)p_;                                                    \
    R1 = *(const f32x4*)(p_ + 4);                                              \
  }
#define AW(g, NS, R0, R1)                                                      \
  {                                                                            \
    bf16x8 v_;                                                                 \
    _Pragma("unroll") for (int j_ = 0; j_ < 4; ++j_) {                         \
      v_[j_] = (__bf16)R0[j_];                                                 \
      v_[4 + j_] = (__bf16)R1[j_];                                             \
    }                                                                          \
    *(bf16x8*)&As[NS][awb##g] = v_;                                            \
  }
#define BG(rd, ktv, NS)                                                        \
  GLOAD_LDS16(pBg + (size_t)(rd)*64 * K + (size_t)(ktv)*64,                    \
              &Bs[NS][((rd)*64 + wid * 8) * 64])

#define LDA(S, KS, mi)                                                         \
  (*(const bf16x8*)&As[S][((KS) ? aoff1 : aoff0) + (mi)*1024])
#define LDB(S, KS, nj)                                                         \
  (*(const bf16x8*)&Bs[S][((KS) ? boff1 : boff0) + (nj)*1024])

#define PH_READ_B(S, KS)                                                       \
  b_[0] = LDB(S, KS, 0);                                                       \
  b_[1] = LDB(S, KS, 1);                                                       \
  b_[2] = LDB(S, KS, 2);                                                       \
  b_[3] = LDB(S, KS, 3);
#define PH_READ_A(S, KS, MB)                                                   \
  a_[0] = LDA(S, KS, MB + 0);                                                  \
  a_[1] = LDA(S, KS, MB + 1);                                                  \
  a_[2] = LDA(S, KS, MB + 2);                                                  \
  a_[3] = LDA(S, KS, MB + 3);

#define PH_MFMA(MB)                                                            \
  LGKM0;                                                                       \
  SB0;                                                                         \
  __builtin_amdgcn_s_setprio(1);                                               \
  _Pragma("unroll") for (int d_ = 0; d_ < 4; ++d_)                             \
      _Pragma("unroll") for (int nj_ = 0; nj_ < 4; ++nj_) acc[(MB) + d_][nj_] =\
          __builtin_amdgcn_mfma_f32_16x16x32_bf16(a_[d_], b_[nj_],             \
                                                  acc[(MB) + d_][nj_], 0, 0,   \
                                                  0);                          \
  __builtin_amdgcn_s_setprio(0);

  // One K-tile = 4 phases. S = current slot, NS = next, ktn = tile staged.
#define ITER(S, NS, ktn, STG)                                                  \
  {                                                                            \
    bf16x8 b_[4], a_[4];                                                       \
    /* ph0: B(ks0) + A(mi0-3,ks0); stage A g0,g1 + B rd0,rd1 */                \
    PH_READ_B(S, 0);                                                           \
    PH_READ_A(S, 0, 0);                                                        \
    SB0;                                                                       \
    if (STG) {                                                                 \
      AL(0, ktn, s00, s01);                                                    \
      AL(1, ktn, s10, s11);                                                    \
      SB0;                                                                     \
      BG(0, ktn, NS);                                                          \
      BG(1, ktn, NS);                                                          \
      SB0;                                                                     \
    }                                                                          \
    BARRIER;                                                                   \
    PH_MFMA(0);                                                                \
    BARRIER;                                                                   \
    /* ph1: A(mi4-7,ks0); vmcnt(2)->write g0,g1; stage g2,g3 + rd2,rd3 */      \
    PH_READ_A(S, 0, 4);                                                        \
    SB0;                                                                       \
    if (STG) {                                                                 \
      VMC(2);                                                                  \
      AW(0, NS, s00, s01);                                                     \
      AW(1, NS, s10, s11);                                                     \
      SB0;                                                                     \
      AL(2, ktn, s00, s01);                                                    \
      AL(3, ktn, s10, s11);                                                    \
      SB0;                                                                     \
      BG(2, ktn, NS);                                                          \
      BG(3, ktn, NS);                                                          \
      SB0;                                                                     \
    }                                                                          \
    BARRIER;                                                                   \
    PH_MFMA(4);                                                                \
    BARRIER;                                                                   \
    /* ph2: B(ks1) + A(mi0-3,ks1); vmcnt(2)->write g2,g3 */                    \
    PH_READ_B(S, 1);                                                           \
    PH_READ_A(S, 1, 0);                                                        \
    SB0;                                                                       \
    if (STG) {                                                                 \
      VMC(2);                                                                  \
      AW(2, NS, s00, s01);                                                     \
      AW(3, NS, s10, s11);                                                     \
      SB0;                                                                     \
    }                                                                          \
    BARRIER;                                                                   \
    PH_MFMA(0);                                                                \
    BARRIER;                                                                   \
    /* ph3: A(mi4-7,ks1); vmcnt(0) (Bg2,Bg3 issued 2 phases ago) */            \
    PH_READ_A(S, 1, 4);                                                        \
    SB0;                                                                       \
    if (STG) {                                                                 \
      VMC(0);                                                                  \
    }                                                                          \
    BARRIER;                                                                   \
    PH_MFMA(4);                                                                \
    LGKM0;                                                                     \
    BARRIER;                                                                   \
  }

  // ---- prologue: stage tile 0 -> slot 0 ----
  f32x4 s00, s01, s10, s11;
  {
    f32x4 s20, s21, s30, s31;
    AL(0, 0, s00, s01);
    AL(1, 0, s10, s11);
    SB0;
    AL(2, 0, s20, s21);
    AL(3, 0, s30, s31);
    SB0;
    BG(0, 0, 0);
    BG(1, 0, 0);
    BG(2, 0, 0);
    BG(3, 0, 0);
    SB0;
    VMC(4);  // 12 outstanding -> 8 A-loads done, 4 B gloads in flight
    AW(0, 0, s00, s01);
    AW(1, 0, s10, s11);
    AW(2, 0, s20, s21);
    AW(3, 0, s30, s31);
    VMC(0);
    LGKM0;
    BARRIER;
  }

  // ---- main loop: 32 K-tiles, unrolled by 2 for literal slots ----
  for (int kt = 0; kt < NK2 - 2; kt += 2) {
    ITER(0, 1, kt + 1, 1);
    ITER(1, 0, kt + 2, 1);
  }
  ITER(0, 1, NK2 - 1, 1);  // it=30 stages tile 31
  ITER(1, 0, 0, 0);        // it=31, no stage

  // ---- epilogue 1: fused column partial stats from live accumulators ----
#pragma unroll
  for (int nj = 0; nj < 4; ++nj) {
    float s = 0.f, q = 0.f;
#pragma unroll
    for (int mi = 0; mi < 8; ++mi)
#pragma unroll
      for (int j = 0; j < 4; ++j) {
        float v = acc[mi][nj][j];
        s += v;
        q += v * v;
      }
    s += __shfl_xor(s, 16);  // reduce over fcb (lane bits 4-5)
    s += __shfl_xor(s, 32);
    q += __shfl_xor(q, 16);
    q += __shfl_xor(q, 32);
    if (fcb == 0) {
      redsum[wr][wc * 64 + nj * 16 + frow] = s;
      redsq[wr][wc * 64 + nj * 16 + frow] = q;
    }
  }
  __syncthreads();
  if (tid < BN) {
    psum[(size_t)tm * N + n0 + tid] = redsum[0][tid] + redsum[1][tid];
    psq[(size_t)tm * N + n0 + tid] = redsq[0][tid] + redsq[1][tid];
  }
  __syncthreads();  // drains vmcnt -> psum/psq stores are in L2

  // ---- per-tn-group ticket: last arriver (of 64) finalizes BN stats ----
  if (tid == 0) {
    __threadfence();  // release: flush this XCD's dirty lines to LLC
    sh_tkt = __hip_atomic_fetch_add(&ctr[tn], 1u, __ATOMIC_RELAXED,
                                    __HIP_MEMORY_SCOPE_AGENT);
  }
  __syncthreads();
  if (sh_tkt == TM2 - 1) {  // leader block: reduce 64 partials -> scale/shift
    if (tid == 0) __threadfence();  // acquire: invalidate stale psum lines
    __syncthreads();
    {
      const int c = tid & 255, h = tid >> 8;
      float s = 0.f, q = 0.f;
      const float* ps = psum + n0 + c;
      const float* pq = psq + n0 + c;
      for (int i = h * 32; i < h * 32 + 32; ++i) {
        s += ps[(size_t)i * N];
        q += pq[(size_t)i * N];
      }
      redsum[h][c] = s;
      redsq[h][c] = q;
    }
    __syncthreads();
    if (tid < BN) {
      const float S = redsum[0][tid] + redsum[1][tid];
      const float Q = redsq[0][tid] + redsq[1][tid];
      const float mean = S * (1.f / (float)M);
      const float var = Q * (1.f / (float)M) - mean * mean;
      const float inv = rsqrtf(var + BN_EPS);
      const float sc = gamma[n0 + tid] * inv;
      scale[n0 + tid] = sc;
      shift[n0 + tid] = beta[n0 + tid] - mean * sc;
    }
    __syncthreads();  // drain scale/shift stores to L2
    if (tid == 0) {
      __threadfence();  // release scale/shift to LLC
      __hip_atomic_store(&ctr[4 + tn], 1u, __ATOMIC_RELAXED,
                         __HIP_MEMORY_SCOPE_AGENT);
    }
  } else {
    if (tid == 0) {
      while (__hip_atomic_load(&ctr[4 + tn], __ATOMIC_RELAXED,
                               __HIP_MEMORY_SCOPE_AGENT) == 0u) {
        __builtin_amdgcn_s_sleep(8);
      }
      __threadfence();  // acquire: invalidate so scale/shift reads are fresh
    }
  }
  __syncthreads();

  // ---- stage scale/shift to LDS, apply to live acc, store Y once ----
  if (tid < BN) {
    redsum[0][tid] = scale[n0 + tid];
    redsq[0][tid] = shift[n0 + tid];
  }
  __syncthreads();
#pragma unroll
  for (int mi = 0; mi < 8; ++mi) {
    const size_t r0 = m0 + wr * 128 + mi * 16 + fcb * 4;
#pragma unroll
    for (int nj = 0; nj < 4; ++nj) {
      const int cloc = wc * 64 + nj * 16 + frow;
      const float sc = redsum[0][cloc];
      const float sh = redsq[0][cloc];
      float* yp = Y + r0 * N + n0 + cloc;
#pragma unroll
      for (int j = 0; j < 4; ++j) yp[(size_t)j * N] = acc[mi][nj][j] * sc + sh;
    }
  }
}

extern "C" void kernel_launch(void* const* d_in, const int* in_sizes, int n_in,
                              void* d_out, int out_size, void* d_ws,
                              size_t ws_size, hipStream_t stream) {
  const float* x = (const float*)d_in[0];
  const float* w = (const float*)d_in[1];
  // d_in[2] = bias: a per-column constant shift cancels exactly in BatchNorm
  const float* gamma = (const float*)d_in[3];
  const float* beta = (const float*)d_in[4];
  float* Y = (float*)d_out;  // written once, already normalized

  char* ws = (char*)d_ws;
  uint4v* wb = (uint4v*)ws;  // 4 MiB
  float* psum = (float*)(ws + (size_t)N * K * 2);
  float* psq = psum + (size_t)TM2 * N;  // 256 KiB each
  float* scale = psq + (size_t)TM2 * N;
  float* shift = scale + N;
  unsigned* ctr = (unsigned*)(shift + N);  // ctr[4] + flag[4]

  binw_kernel<<<(N * K / 8) / 256, 256, 0, stream>>>(w, wb, ctr);

  const float* xp = x;
  const unsigned short* Bp = (const unsigned short*)wb;
  void* args[] = {(void*)&xp,    (void*)&Bp,    (void*)&Y,
                  (void*)&psum,  (void*)&psq,   (void*)&scale,
                  (void*)&shift, (void*)&gamma, (void*)&beta,
                  (void*)&ctr};
  // grid 256 = 1 block/CU (132 KB LDS) -> co-residency guaranteed
  hipLaunchCooperativeKernel(reinterpret_cast<void*>(gemm_bin_kernel),
                             dim3(GRID), dim3(512), args, 0, stream);
}